// Round 1
// baseline (451.777 us; speedup 1.0000x reference)
//
#include <hip/hip_runtime.h>

// MaxoutDynamic: per row of [B, 4096] fp32, zero the 2048 smallest values,
// scale the 2048 survivors by 4096/2048 = 2.0.
//
// v2: one WAVE per row (4 rows per 256-thread block), fully barrier-free.
//  - 64 values/lane held in VGPRs (16x float4).
//  - Exact selection of the rank-2048 (0-indexed) value:
//      pass 1: count n_lo = #(x < -0.125) (pure shuffle reduce, no LDS) and
//              build a 256-bin FINE histogram over [-0.125, 0.125) -- the
//              sample median of 4096 N(0,1) draws is 0 +/- ~0.02, so the
//              rank-2048 value lies in this band except at ~6.4 sigma
//              (P ~ 8e-11/row); only ~10% of elements touch LDS atomics.
//      pass 2: conflict-free uint4 scan of 256 bins by one wave -> bin + rank.
//      pass 3: gather that bin's ~2 candidates, all-pairs rank -> exact tau.
//      fallback (wave-uniform, effectively never taken): wide 256-bin
//              histogram over [-4,4) -- same machinery, exact for any data
//              up to CAP candidates per selected bin (same acceptance as v1).
//  - Wave-private LDS regions; ordering via s_waitcnt lgkmcnt(0) fences
//    (a wave's DS ops all retire before the waitcnt clears; lanes of a wave
//    share one instruction stream, so no barrier is needed).
//  - Keep rule identical to the verified v1: out = (v >= tau) ? 2v : 0.

#define FEAT   4096
#define NDROP  2048
#define TPB    256
#define RPB    4          // rows (= waves) per block
#define NBIN   256        // bins (fine pass and fallback wide pass)
#define CAP    128        // candidate list capacity (fine path expects ~2)

#define LDS_FENCE() asm volatile("s_waitcnt lgkmcnt(0)" ::: "memory")

// Wave-wide: given a 256-bin histogram and target rank rel (within the
// histogrammed population), find the bin containing rank rel and the rank
// within that bin. Returns false if rel < 0 or rel >= total count.
__device__ __forceinline__ bool pick_bin(const unsigned int* __restrict__ hist,
                                         int lane, int rel,
                                         int& selbin, unsigned int& rrout) {
    const uint4 c4 = ((const uint4*)hist)[lane];          // 4 bins/lane, conflict-free b128
    const unsigned int csum = c4.x + c4.y + c4.z + c4.w;
    unsigned int incl = csum;
#pragma unroll
    for (int d = 1; d < 64; d <<= 1) {
        unsigned int y = __shfl_up(incl, d, 64);
        if (lane >= d) incl += y;
    }
    const unsigned int excl = incl - csum;
    const bool has = (rel >= 0) && ((unsigned)rel >= excl) &&
                     ((unsigned)rel < excl + csum);
    const unsigned long long bal = __ballot(has);
    if (bal == 0ull) return false;
    const int src = (int)(__ffsll(bal) - 1);
    int pack = 0;
    if (has) {
        unsigned int rr = (unsigned)rel - excl;
        int bsel;
        if (rr < c4.x) { bsel = 0; }
        else {
            rr -= c4.x;
            if (rr < c4.y) { bsel = 1; }
            else {
                rr -= c4.y;
                if (rr < c4.z) { bsel = 2; }
                else { rr -= c4.z; bsel = 3; }
            }
        }
        pack = ((lane * 4 + bsel) << 16) | (int)rr;
    }
    pack = __shfl(pack, src, 64);
    selbin = pack >> 16;
    rrout  = (unsigned)(pack & 0xffff);
    return true;
}

// Wave-wide all-pairs rank among n candidates in LDS -> the value of rank rr.
__device__ __forceinline__ float rank_tau(const float* __restrict__ list,
                                          int n, unsigned int rr, int lane) {
    float tauv = 0.0f;
    bool  got  = false;
    for (int c0 = lane; c0 < n; c0 += 64) {
        const float vc = list[c0];
        unsigned int r = 0u, mm = 0u;
        for (int j = 0; j < n; ++j) {
            const float vj = list[j];                 // same addr all lanes -> broadcast
            r  += (vj <  vc) ? 1u : 0u;
            mm += (vj == vc) ? 1u : 0u;
        }
        if (r <= rr && rr < r + mm) { tauv = vc; got = true; }  // ties: same bits
    }
    const unsigned long long gm = __ballot(got);
    const int s2 = gm ? (int)(__ffsll(gm) - 1) : 0;
    return __shfl(tauv, s2, 64);
}

__global__ __launch_bounds__(TPB, 4)
void MaxoutDynamic_55181739819231_kernel(const float* __restrict__ in,
                                         float* __restrict__ out,
                                         int rows) {
    const int wave = threadIdx.x >> 6;
    const int lane = threadIdx.x & 63;
    const int row  = blockIdx.x * RPB + wave;
    if (row >= rows) return;            // wave-uniform; no barriers anywhere

    __shared__ __align__(16) unsigned int hist_s[RPB][NBIN];
    __shared__ float                      list_s[RPB][CAP];
    __shared__ unsigned int               cnt_s[RPB];

    unsigned int* hist = hist_s[wave];   // wave-private regions
    float*        list = list_s[wave];

    const float4* inrow  = (const float4*)(in  + (size_t)row * FEAT);
    float4*       outrow = (float4*)      (out + (size_t)row * FEAT);

    // ---- load row: lane owns float4 indices {lane, lane+64, ..., lane+960} ----
    float4 xs[16];
#pragma unroll
    for (int j = 0; j < 16; ++j) xs[j] = inrow[lane + j * 64];

    // ---- zero fine histogram (4 bins/lane, one b128 store) ----
    ((uint4*)hist)[lane] = make_uint4(0u, 0u, 0u, 0u);
    if (lane == 0) cnt_s[wave] = 0u;
    LDS_FENCE();

    // ---- pass 1: n_lo = #(x < -0.125); fine histogram of [-0.125, 0.125) ----
    const float LO = -0.125f, HI = 0.125f;
    int nlo = 0;
#pragma unroll
    for (int j = 0; j < 16; ++j) {
        const float v[4] = {xs[j].x, xs[j].y, xs[j].z, xs[j].w};
#pragma unroll
        for (int k = 0; k < 4; ++k) {
            const float x = v[k];
            nlo += (x < LO) ? 1 : 0;
            if (x >= LO && x < HI) {
                int b = (int)((x - LO) * 1024.0f);   // 256 bins over width 0.25
                b = b > (NBIN - 1) ? (NBIN - 1) : b; // fp edge safety
                atomicAdd(&hist[b], 1u);
            }
        }
    }
#pragma unroll
    for (int d = 1; d < 64; d <<= 1) nlo += __shfl_xor(nlo, d, 64);
    LDS_FENCE();

    float tau;
    int selbin;
    unsigned int rr;
    if (pick_bin(hist, lane, NDROP - nlo, selbin, rr)) {
        // ---- gather the selected fine bin's candidates ----
#pragma unroll
        for (int j = 0; j < 16; ++j) {
            const float v[4] = {xs[j].x, xs[j].y, xs[j].z, xs[j].w};
#pragma unroll
            for (int k = 0; k < 4; ++k) {
                const float x = v[k];
                if (x >= LO && x < HI) {
                    int b = (int)((x - LO) * 1024.0f);
                    b = b > (NBIN - 1) ? (NBIN - 1) : b;
                    if (b == selbin) {
                        unsigned int idx = atomicAdd(&cnt_s[wave], 1u);
                        if (idx < CAP) list[idx] = x;
                    }
                }
            }
        }
        LDS_FENCE();
        int n = (int)cnt_s[wave];
        n = n > CAP ? CAP : n;
        tau = rank_tau(list, n, rr, lane);
    } else {
        // ---- fallback: wide 256-bin histogram over [-4,4), clamped tails ----
        ((uint4*)hist)[lane] = make_uint4(0u, 0u, 0u, 0u);
        LDS_FENCE();
#pragma unroll
        for (int j = 0; j < 16; ++j) {
            const float v[4] = {xs[j].x, xs[j].y, xs[j].z, xs[j].w};
#pragma unroll
            for (int k = 0; k < 4; ++k) {
                int b = (int)((v[k] + 4.0f) * 32.0f);
                b = b < 0 ? 0 : (b > (NBIN - 1) ? (NBIN - 1) : b);
                atomicAdd(&hist[b], 1u);
            }
        }
        LDS_FENCE();
        pick_bin(hist, lane, NDROP, selbin, rr);   // total=4096 > NDROP: always true
#pragma unroll
        for (int j = 0; j < 16; ++j) {
            const float v[4] = {xs[j].x, xs[j].y, xs[j].z, xs[j].w};
#pragma unroll
            for (int k = 0; k < 4; ++k) {
                int b = (int)((v[k] + 4.0f) * 32.0f);
                b = b < 0 ? 0 : (b > (NBIN - 1) ? (NBIN - 1) : b);
                if (b == selbin) {
                    unsigned int idx = atomicAdd(&cnt_s[wave], 1u);
                    if (idx < CAP) list[idx] = v[k];
                }
            }
        }
        LDS_FENCE();
        int n = (int)cnt_s[wave];
        n = n > CAP ? CAP : n;
        tau = rank_tau(list, n, rr, lane);
    }

    // ---- write: keep (x2) if v >= tau, else 0 ----
#pragma unroll
    for (int j = 0; j < 16; ++j) {
        float4 o;
        o.x = (xs[j].x >= tau) ? 2.0f * xs[j].x : 0.0f;
        o.y = (xs[j].y >= tau) ? 2.0f * xs[j].y : 0.0f;
        o.z = (xs[j].z >= tau) ? 2.0f * xs[j].z : 0.0f;
        o.w = (xs[j].w >= tau) ? 2.0f * xs[j].w : 0.0f;
        outrow[lane + j * 64] = o;
    }
}

extern "C" void kernel_launch(void* const* d_in, const int* in_sizes, int n_in,
                              void* d_out, int out_size, void* d_ws, size_t ws_size,
                              hipStream_t stream) {
    const float* feat = (const float*)d_in[0];
    float* out = (float*)d_out;
    const int rows = in_sizes[0] / FEAT;   // 16384
    const int grid = (rows + RPB - 1) / RPB;
    MaxoutDynamic_55181739819231_kernel<<<grid, TPB, 0, stream>>>(feat, out, rows);
}

// Round 2
// 411.042 us; speedup vs baseline: 1.0991x; 1.0991x over previous
//
#include <hip/hip_runtime.h>

// MaxoutDynamic: per row of [B, 4096] fp32, zero the 2048 smallest values,
// scale the 2048 survivors by 4096/2048 = 2.0.
//
// v3: block-per-row (v1's measured-better structure) + v2's narrow-band
// selection machinery.
//  - 256 threads/block, 16 values/thread in VGPRs (4x float4) -> ~48 VGPRs,
//    8 waves/SIMD occupancy (v2's wave-per-row needed 64 data regs -> 4/SIMD).
//  - Exact rank-2048 (0-indexed) selection:
//      pass 1: nlo = #(x < -0.125) via shuffle+1 atomic/wave; 256-bin FINE
//              histogram over [-0.125, 0.125). Sample median of 4096 N(0,1)
//              draws is 0 +/- ~0.02, so the rank-2048 value lies in-band
//              except at ~6.4 sigma (P ~ 8e-11/row); only ~10% of elements
//              touch LDS atomics (410/row vs v1's 4096/row).
//      pass 2: wave0 conflict-free uint4 scan of 256 bins -> bin + rank-in-bin
//              (v1 scanned 1024 bins with a 32-way bank conflict per read).
//      pass 3: gather that bin's ~2 candidates, all-pairs rank -> exact tau.
//      fallback (block-uniform, effectively never taken): wide 256-bin
//              histogram over [-4,4), same machinery -> exact for any data.
//  - Nontemporal loads/stores: pure streaming, no reuse, keep L2 clean.
//  - Keep rule identical to the verified versions: out = (v >= tau) ? 2v : 0.
// 5 barriers/block on the fine path.

#define FEAT   4096
#define NDROP  2048
#define TPB    256
#define NBIN   256        // == TPB (zeroing assumes this)
#define CAP    256        // candidate list capacity (fine path expects ~2)

typedef float f32x4 __attribute__((ext_vector_type(4)));

__global__ __launch_bounds__(TPB)
void MaxoutDynamic_55181739819231_kernel(const float* __restrict__ in,
                                         float* __restrict__ out) {
    const int row  = blockIdx.x;
    const int t    = threadIdx.x;
    const int lane = t & 63;
    const int wid  = t >> 6;

    const f32x4* inrow  = (const f32x4*)(in  + (size_t)row * FEAT);
    f32x4*       outrow = (f32x4*)      (out + (size_t)row * FEAT);

    __shared__ __align__(16) unsigned int hist[NBIN];
    __shared__ float        list[CAP];
    __shared__ unsigned int s_cnt;
    __shared__ unsigned int s_nlo;
    __shared__ unsigned int s_bin;
    __shared__ unsigned int s_rank;
    __shared__ unsigned int s_found;
    __shared__ float        s_tau;

    // ---- load row: thread t owns float4 indices {t, t+256, t+512, t+768} ----
    f32x4 xs[4];
#pragma unroll
    for (int j = 0; j < 4; ++j)
        xs[j] = __builtin_nontemporal_load(&inrow[t + j * TPB]);

    // ---- zero histogram / scalars (NBIN == TPB: one store per thread) ----
    hist[t] = 0u;
    if (t == 0) { s_cnt = 0u; s_nlo = 0u; s_found = 0u; s_tau = 0.0f; }
    __syncthreads();

    // ---- pass 1: nlo count + fine histogram of [-0.125, 0.125) ----
    const float LO = -0.125f, HI = 0.125f;
    int nlo = 0;
#pragma unroll
    for (int j = 0; j < 4; ++j) {
#pragma unroll
        for (int k = 0; k < 4; ++k) {
            const float x = xs[j][k];
            nlo += (x < LO) ? 1 : 0;
            if (x >= LO && x < HI) {
                int b = (int)((x - LO) * 1024.0f);   // 256 bins over width 0.25
                b = b > (NBIN - 1) ? (NBIN - 1) : b; // fp edge safety
                atomicAdd(&hist[b], 1u);
            }
        }
    }
#pragma unroll
    for (int d = 1; d < 64; d <<= 1) nlo += __shfl_xor(nlo, d, 64);
    if (lane == 0) atomicAdd(&s_nlo, (unsigned)nlo);
    __syncthreads();

    // ---- pass 2: wave0 scans 256 bins (4/lane, conflict-free b128 read) ----
    if (wid == 0) {
        const int rel = NDROP - (int)s_nlo;
        const uint4 c4 = ((const uint4*)hist)[lane];
        const unsigned int csum = c4.x + c4.y + c4.z + c4.w;
        unsigned int incl = csum;
#pragma unroll
        for (int d = 1; d < 64; d <<= 1) {
            unsigned int y = __shfl_up(incl, d, 64);
            if (lane >= d) incl += y;
        }
        const unsigned int excl = incl - csum;
        if (rel >= 0 && (unsigned)rel >= excl && (unsigned)rel < excl + csum) {
            unsigned int rr = (unsigned)rel - excl;
            int bsel;
            if (rr < c4.x) { bsel = 0; }
            else {
                rr -= c4.x;
                if (rr < c4.y) { bsel = 1; }
                else {
                    rr -= c4.y;
                    if (rr < c4.z) { bsel = 2; }
                    else { rr -= c4.z; bsel = 3; }
                }
            }
            s_bin   = (unsigned)(lane * 4 + bsel);
            s_rank  = rr;
            s_found = 1u;
        }
    }
    __syncthreads();

    if (s_found) {          // block-uniform branch
        // ---- pass 3: gather the selected fine bin's candidates ----
        const unsigned int selbin = s_bin;
#pragma unroll
        for (int j = 0; j < 4; ++j) {
#pragma unroll
            for (int k = 0; k < 4; ++k) {
                const float x = xs[j][k];
                if (x >= LO && x < HI) {
                    int b = (int)((x - LO) * 1024.0f);
                    b = b > (NBIN - 1) ? (NBIN - 1) : b;
                    if ((unsigned)b == selbin) {
                        unsigned int idx = atomicAdd(&s_cnt, 1u);
                        if (idx < CAP) list[idx] = x;
                    }
                }
            }
        }
        __syncthreads();
    } else {
        // ---- fallback: wide 256-bin histogram over [-4,4), clamped tails ----
        hist[t] = 0u;
        __syncthreads();
#pragma unroll
        for (int j = 0; j < 4; ++j) {
#pragma unroll
            for (int k = 0; k < 4; ++k) {
                int b = (int)((xs[j][k] + 4.0f) * 32.0f);
                b = b < 0 ? 0 : (b > (NBIN - 1) ? (NBIN - 1) : b);
                atomicAdd(&hist[b], 1u);
            }
        }
        __syncthreads();
        if (wid == 0) {     // total = 4096 > NDROP: a bin is always found
            const uint4 c4 = ((const uint4*)hist)[lane];
            const unsigned int csum = c4.x + c4.y + c4.z + c4.w;
            unsigned int incl = csum;
#pragma unroll
            for (int d = 1; d < 64; d <<= 1) {
                unsigned int y = __shfl_up(incl, d, 64);
                if (lane >= d) incl += y;
            }
            const unsigned int excl = incl - csum;
            if ((unsigned)NDROP >= excl && (unsigned)NDROP < excl + csum) {
                unsigned int rr = (unsigned)NDROP - excl;
                int bsel;
                if (rr < c4.x) { bsel = 0; }
                else {
                    rr -= c4.x;
                    if (rr < c4.y) { bsel = 1; }
                    else {
                        rr -= c4.y;
                        if (rr < c4.z) { bsel = 2; }
                        else { rr -= c4.z; bsel = 3; }
                    }
                }
                s_bin  = (unsigned)(lane * 4 + bsel);
                s_rank = rr;
            }
        }
        __syncthreads();
        const unsigned int selbin = s_bin;
#pragma unroll
        for (int j = 0; j < 4; ++j) {
#pragma unroll
            for (int k = 0; k < 4; ++k) {
                const float x = xs[j][k];
                int b = (int)((x + 4.0f) * 32.0f);
                b = b < 0 ? 0 : (b > (NBIN - 1) ? (NBIN - 1) : b);
                if ((unsigned)b == selbin) {
                    unsigned int idx = atomicAdd(&s_cnt, 1u);
                    if (idx < CAP) list[idx] = x;
                }
            }
        }
        __syncthreads();
    }

    // ---- pass 4: wave0 all-pairs rank among n candidates -> tau ----
    if (wid == 0) {
        int n = (int)s_cnt; if (n > CAP) n = CAP;
        const unsigned int rr = s_rank;
        for (int c0 = lane; c0 < n; c0 += 64) {
            const float vc = list[c0];
            unsigned int r = 0u, m = 0u;
            for (int j = 0; j < n; ++j) {
                const float vj = list[j];     // same addr all lanes -> broadcast
                r += (vj <  vc) ? 1u : 0u;
                m += (vj == vc) ? 1u : 0u;
            }
            if (r <= rr && rr < r + m) s_tau = vc;   // ties: all write same bits
        }
    }
    __syncthreads();
    const float tau = s_tau;

    // ---- write: keep (x2) if v >= tau, else 0; nontemporal stores ----
#pragma unroll
    for (int j = 0; j < 4; ++j) {
        f32x4 o;
#pragma unroll
        for (int k = 0; k < 4; ++k)
            o[k] = (xs[j][k] >= tau) ? 2.0f * xs[j][k] : 0.0f;
        __builtin_nontemporal_store(o, &outrow[t + j * TPB]);
    }
}

extern "C" void kernel_launch(void* const* d_in, const int* in_sizes, int n_in,
                              void* d_out, int out_size, void* d_ws, size_t ws_size,
                              hipStream_t stream) {
    const float* feat = (const float*)d_in[0];
    float* out = (float*)d_out;
    const int rows = in_sizes[0] / FEAT;   // 16384
    MaxoutDynamic_55181739819231_kernel<<<rows, TPB, 0, stream>>>(feat, out);
}